// Round 3
// baseline (896.914 us; speedup 1.0000x reference)
//
#include <hip/hip_runtime.h>
#include <math.h>

#define NN 100000
#define NE 3200000
#define INC 128
#define HID 16
#define OC 40

#define BSH 7                      // 128 nodes per bucket
#define BNODES 128
#define NB ((NN + BNODES - 1) >> BSH)  // 782
#define CAP 4608                   // mean 4096 + 8 sigma
#define CSTRIDE 16                 // cursor padded to one 64B line each

__global__ void k_zero_i(int* __restrict__ p, int n) {
    int i = blockIdx.x * blockDim.x + threadIdx.x;
    if (i < n) p[i] = 0;
}

// bin edges by dst bucket; packed word = (dst&127)<<25 | src
__global__ void k_bin(const int* __restrict__ src, const int* __restrict__ dst,
                      int* __restrict__ cursor, int* __restrict__ bin) {
    int e = blockIdx.x * blockDim.x + threadIdx.x;
    if (e >= NE) return;
    unsigned s = (unsigned)src[e], d = (unsigned)dst[e];
    if (s >= NN || d >= NN) return;  // defensive
    int b = d >> BSH;
    int p = atomicAdd(&cursor[b * CSTRIDE], 1);
    if (p < CAP) bin[(size_t)b * CAP + p] = (int)(((d & (BNODES - 1)) << 25) | s);
}

// per-bucket degree histogram -> dis = rsqrt(deg+1)
__global__ __launch_bounds__(256) void k_degdis(const int* __restrict__ bin,
                                                const int* __restrict__ cursor,
                                                float* __restrict__ dis) {
    __shared__ int degl[BNODES];
    int b = blockIdx.x, t = threadIdx.x;
    if (t < BNODES) degl[t] = 0;
    __syncthreads();
    int cnt = cursor[b * CSTRIDE];
    if (cnt > CAP) cnt = CAP;
    for (int e = t; e < cnt; e += 256) {
        unsigned w = (unsigned)bin[(size_t)b * CAP + e];
        atomicAdd(&degl[w >> 25], 1);
    }
    __syncthreads();
    if (t < BNODES) {
        int node = (b << BSH) + t;
        if (node < NN) dis[node] = rsqrtf((float)(degl[t] + 1));
    }
}

// g1 = dis[i] * (x @ W1)[i]  : [NN,128]@[128,16] scaled
__global__ __launch_bounds__(256) void k_gemm1(const float* __restrict__ x,
                                               const float* __restrict__ W1,
                                               const float* __restrict__ dis,
                                               float* __restrict__ g1) {
    __shared__ float xs[16][INC + 1];
    __shared__ float ws[INC][HID];
    int t = threadIdx.x;
    int rowbase = blockIdx.x * 16;  // NN/16 = 6250 exact
#pragma unroll
    for (int i = 0; i < 8; ++i) {
        int idx = t + i * 256;
        xs[idx >> 7][idx & 127] = x[(long long)(rowbase)*INC + idx];
    }
#pragma unroll
    for (int i = 0; i < 8; ++i) {
        int idx = t + i * 256;
        ws[idx >> 4][idx & 15] = W1[idx];
    }
    __syncthreads();
    int r = t >> 4, c = t & 15;
    float acc = 0.f;
#pragma unroll
    for (int k = 0; k < INC; ++k) acc += xs[r][k] * ws[k][c];
    int row = rowbase + r;
    g1[row * HID + c] = dis[row] * acc;
}

// Aggregate: agg[dl][c] = sum_{edges into node} gin[src][c]  (LDS accumulator)
// epilogue: val = dis_i * (agg + gin[i])        [= GCN conv output pre-bias]
//   mode 1: val = relu(val + bias) * dis_i      -> writes g2 for next layer
//   mode 0: val as-is                           -> logits input for k_final
__global__ __launch_bounds__(256) void k_agg(const float* __restrict__ gin,
                                             const float* __restrict__ dis,
                                             const int* __restrict__ bin,
                                             const int* __restrict__ cursor,
                                             const float* __restrict__ bias,
                                             float* __restrict__ outp, int mode) {
    __shared__ float agg[BNODES * HID];  // 8KB
    __shared__ float disl[BNODES];
    int b = blockIdx.x, t = threadIdx.x;
    for (int i = t; i < BNODES * HID; i += 256) agg[i] = 0.f;
    if (t < BNODES) {
        int node = (b << BSH) + t;
        disl[t] = (node < NN) ? dis[node] : 0.f;
    }
    __syncthreads();
    int cnt = cursor[b * CSTRIDE];
    if (cnt > CAP) cnt = CAP;
    int g = t >> 4, c = t & 15;
    const int* bb = bin + (size_t)b * CAP;
    int e = g;
    for (; e + 16 < cnt; e += 32) {
        unsigned w0 = (unsigned)bb[e];
        unsigned w1 = (unsigned)bb[e + 16];
        float v0 = gin[(w0 & 0x1FFFFFF) * HID + c];
        float v1 = gin[(w1 & 0x1FFFFFF) * HID + c];
        atomicAdd(&agg[(w0 >> 25) * HID + c], v0);
        atomicAdd(&agg[(w1 >> 25) * HID + c], v1);
    }
    if (e < cnt) {
        unsigned w0 = (unsigned)bb[e];
        atomicAdd(&agg[(w0 >> 25) * HID + c], gin[(w0 & 0x1FFFFFF) * HID + c]);
    }
    __syncthreads();
    for (int i = t; i < BNODES * HID; i += 256) {
        int dl = i >> 4, cc = i & 15;
        int node = (b << BSH) + dl;
        if (node < NN) {
            float di = disl[dl];
            float val = di * (agg[i] + gin[node * HID + cc]);
            if (mode) val = fmaxf(val + bias[cc], 0.f) * di;
            outp[node * HID + cc] = val;
        }
    }
}

// out[i] = log_softmax(in[i] @ W2 + b2)  (in = aggregated layer-2 pre-bias)
__global__ __launch_bounds__(256) void k_final(const float* __restrict__ in2,
                                               const float* __restrict__ W2,
                                               const float* __restrict__ b2,
                                               float* __restrict__ out) {
    __shared__ float w2s[HID * OC];
    __shared__ float b2s[OC];
    int t = threadIdx.x;
    for (int i = t; i < HID * OC; i += 256) w2s[i] = W2[i];
    if (t < OC) b2s[t] = b2[t];
    __syncthreads();
    int row = blockIdx.x * 256 + t;
    if (row >= NN) return;
    float a[HID];
#pragma unroll
    for (int k = 0; k < HID; ++k) a[k] = in2[row * HID + k];
    float z[OC];
#pragma unroll
    for (int c = 0; c < OC; ++c) z[c] = b2s[c];
#pragma unroll
    for (int k = 0; k < HID; ++k) {
        float av = a[k];
#pragma unroll
        for (int c = 0; c < OC; ++c) z[c] += av * w2s[k * OC + c];
    }
    float m = z[0];
#pragma unroll
    for (int c = 1; c < OC; ++c) m = fmaxf(m, z[c]);
    float ssum = 0.f;
#pragma unroll
    for (int c = 0; c < OC; ++c) ssum += expf(z[c] - m);
    float lse = m + logf(ssum);
#pragma unroll
    for (int c = 0; c < OC; ++c) out[row * OC + c] = z[c] - lse;
}

extern "C" void kernel_launch(void* const* d_in, const int* in_sizes, int n_in,
                              void* d_out, int out_size, void* d_ws, size_t ws_size,
                              hipStream_t stream) {
    const float* x  = (const float*)d_in[0];
    const int*   ei = (const int*)d_in[1];
    const float* W1 = (const float*)d_in[2];
    const float* b1 = (const float*)d_in[3];
    const float* W2 = (const float*)d_in[4];
    const float* b2 = (const float*)d_in[5];
    float* out = (float*)d_out;

    const int* src = ei;       // edge_index[0]
    const int* dst = ei + NE;  // edge_index[1]

    char* ws = (char*)d_ws;
    size_t o = 0;
    int*   cursor = (int*)(ws + o);   o += (size_t)NB * CSTRIDE * 4;  // 50KB
    float* dis    = (float*)(ws + o); o += (size_t)NN * 4;            // 400KB
    int*   bin    = (int*)(ws + o);   o += (size_t)NB * CAP * 4;      // 14.4MB
    float* bufA   = (float*)(ws + o); o += (size_t)NN * HID * 4;      // 6.4MB
    float* bufB   = (float*)(ws + o); o += (size_t)NN * HID * 4;      // 6.4MB

    dim3 B(256);
    int gE = (NE + 255) / 256;
    int gC = (NB * CSTRIDE + 255) / 256;
    int gN = (NN + 255) / 256;

    k_zero_i<<<gC, B, 0, stream>>>(cursor, NB * CSTRIDE);
    k_bin<<<gE, B, 0, stream>>>(src, dst, cursor, bin);
    k_degdis<<<NB, B, 0, stream>>>(bin, cursor, dis);
    k_gemm1<<<NN / 16, B, 0, stream>>>(x, W1, dis, bufA);
    k_agg<<<NB, B, 0, stream>>>(bufA, dis, bin, cursor, b1, bufB, 1);
    k_agg<<<NB, B, 0, stream>>>(bufB, dis, bin, cursor, b2, bufA, 0);
    k_final<<<gN, B, 0, stream>>>(bufA, W2, b2, out);
}

// Round 4
// 332.537 us; speedup vs baseline: 2.6972x; 2.6972x over previous
//
#include <hip/hip_runtime.h>
#include <math.h>

#define NN 100000
#define NE 3200000
#define INC 128
#define HID 16
#define OC 40

#define BSH 6
#define BNODES 64                       // nodes per bucket
#define NB 1563                         // ceil(NN/64)
#define CAP 2432                        // mean 2047 + 8.5 sigma
#define CSTRIDE 16                      // one 64B line per cursor

__global__ void k_zero_i(int* __restrict__ p, int n) {
    int i = blockIdx.x * blockDim.x + threadIdx.x;
    if (i < n) p[i] = 0;
}

// bin edges by dst bucket; packed word = (dst&63)<<26 | src  (src < 2^17)
__global__ void k_bin(const int* __restrict__ src, const int* __restrict__ dst,
                      int* __restrict__ cursor, int* __restrict__ bin) {
    int e = blockIdx.x * blockDim.x + threadIdx.x;
    if (e >= NE) return;
    unsigned s = (unsigned)src[e], d = (unsigned)dst[e];
    if (s >= NN || d >= NN) return;  // defensive
    int b = d >> BSH;
    int p = atomicAdd(&cursor[b * CSTRIDE], 1);
    if (p < CAP) bin[(size_t)b * CAP + p] = (int)(((d & (BNODES - 1)) << 26) | s);
}

// per-bucket LDS counting sort (in place): bin becomes src-sorted-by-local-dst;
// emits off/end per node and dis = rsqrt(deg+1)
__global__ __launch_bounds__(256) void k_sort(int* __restrict__ bin,
                                              const int* __restrict__ cursor,
                                              int* __restrict__ off, int* __restrict__ endv,
                                              float* __restrict__ dis) {
    __shared__ unsigned raw[CAP];
    __shared__ unsigned sorted[CAP];
    __shared__ int hist[BNODES];
    __shared__ int pref[BNODES];
    __shared__ int lcur[BNODES];
    int b = blockIdx.x, t = threadIdx.x;
    int cnt = cursor[b * CSTRIDE];
    if (cnt > CAP) cnt = CAP;
    if (t < BNODES) hist[t] = 0;
    __syncthreads();
    for (int i = t; i < cnt; i += 256) {
        unsigned w = (unsigned)bin[(size_t)b * CAP + i];
        raw[i] = w;
        atomicAdd(&hist[w >> 26], 1);
    }
    __syncthreads();
    if (t < BNODES) pref[t] = hist[t];
    __syncthreads();
    for (int d = 1; d < BNODES; d <<= 1) {
        int add = (t >= d && t < BNODES) ? pref[t - d] : 0;
        __syncthreads();
        if (t < BNODES) pref[t] += add;
        __syncthreads();
    }
    if (t < BNODES) lcur[t] = pref[t] - hist[t];  // exclusive prefix
    __syncthreads();
    for (int i = t; i < cnt; i += 256) {
        unsigned w = raw[i];
        int p = atomicAdd(&lcur[w >> 26], 1);
        sorted[p] = w & 0x1FFFF;  // keep src only
    }
    __syncthreads();
    for (int i = t; i < cnt; i += 256) bin[(size_t)b * CAP + i] = (int)sorted[i];
    if (t < BNODES) {
        int node = (b << BSH) + t;
        if (node < NN) {
            int base = b * CAP;
            off[node]  = base + pref[t] - hist[t];
            endv[node] = base + pref[t];
            dis[node]  = rsqrtf((float)(hist[t] + 1));  // +1 self-loop
        }
    }
}

// g1 = dis[i] * (x @ W1)[i]
__global__ __launch_bounds__(256) void k_gemm1(const float* __restrict__ x,
                                               const float* __restrict__ W1,
                                               const float* __restrict__ dis,
                                               float* __restrict__ g1) {
    __shared__ float xs[16][INC + 1];
    __shared__ float ws[INC][HID];
    int t = threadIdx.x;
    int rowbase = blockIdx.x * 16;  // NN/16 = 6250 exact
#pragma unroll
    for (int i = 0; i < 8; ++i) {
        int idx = t + i * 256;
        xs[idx >> 7][idx & 127] = x[(long long)(rowbase)*INC + idx];
    }
#pragma unroll
    for (int i = 0; i < 8; ++i) {
        int idx = t + i * 256;
        ws[idx >> 4][idx & 15] = W1[idx];
    }
    __syncthreads();
    int r = t >> 4, c = t & 15;
    float acc = 0.f;
#pragma unroll
    for (int k = 0; k < INC; ++k) acc += xs[r][k] * ws[k][c];
    int row = rowbase + r;
    g1[row * HID + c] = dis[row] * acc;
}

// out[i] = di*(sum_{s in-edges} gin[s] + gin[i]);  mode1: relu(+bias)*di (next g)
// 4 lanes per node, float4 per lane; 64 nodes per 256-block
__global__ __launch_bounds__(256) void k_gather(const float* __restrict__ gin,
                                                const float* __restrict__ dis,
                                                const int* __restrict__ off,
                                                const int* __restrict__ endv,
                                                const int* __restrict__ bin,
                                                const float* __restrict__ bias,
                                                float* __restrict__ outp, int mode) {
    int t = threadIdx.x;
    int node = blockIdx.x * 64 + (t >> 2);
    if (node >= NN) return;
    int c4 = t & 3;
    const float4* gv = (const float4*)gin;
    float4 acc = gv[node * 4 + c4];  // self contribution g_i
    int j = off[node], end = endv[node];
    for (; j + 3 < end; j += 4) {
        int s0 = bin[j], s1 = bin[j + 1], s2 = bin[j + 2], s3 = bin[j + 3];
        float4 v0 = gv[s0 * 4 + c4];
        float4 v1 = gv[s1 * 4 + c4];
        float4 v2 = gv[s2 * 4 + c4];
        float4 v3 = gv[s3 * 4 + c4];
        acc.x += (v0.x + v1.x) + (v2.x + v3.x);
        acc.y += (v0.y + v1.y) + (v2.y + v3.y);
        acc.z += (v0.z + v1.z) + (v2.z + v3.z);
        acc.w += (v0.w + v1.w) + (v2.w + v3.w);
    }
    for (; j < end; ++j) {
        int s = bin[j];
        float4 v = gv[s * 4 + c4];
        acc.x += v.x; acc.y += v.y; acc.z += v.z; acc.w += v.w;
    }
    float di = dis[node];
    float4 val;
    val.x = di * acc.x; val.y = di * acc.y; val.z = di * acc.z; val.w = di * acc.w;
    if (mode) {
        val.x = fmaxf(val.x + bias[c4 * 4 + 0], 0.f) * di;
        val.y = fmaxf(val.y + bias[c4 * 4 + 1], 0.f) * di;
        val.z = fmaxf(val.z + bias[c4 * 4 + 2], 0.f) * di;
        val.w = fmaxf(val.w + bias[c4 * 4 + 3], 0.f) * di;
    }
    ((float4*)outp)[node * 4 + c4] = val;
}

// out[i] = log_softmax(in2[i] @ W2 + b2)
__global__ __launch_bounds__(256) void k_final(const float* __restrict__ in2,
                                               const float* __restrict__ W2,
                                               const float* __restrict__ b2,
                                               float* __restrict__ out) {
    __shared__ float w2s[HID * OC];
    __shared__ float b2s[OC];
    int t = threadIdx.x;
    for (int i = t; i < HID * OC; i += 256) w2s[i] = W2[i];
    if (t < OC) b2s[t] = b2[t];
    __syncthreads();
    int row = blockIdx.x * 256 + t;
    if (row >= NN) return;
    float a[HID];
    const float4* iv = (const float4*)(in2 + row * HID);
#pragma unroll
    for (int q = 0; q < 4; ++q) {
        float4 v = iv[q];
        a[q * 4 + 0] = v.x; a[q * 4 + 1] = v.y; a[q * 4 + 2] = v.z; a[q * 4 + 3] = v.w;
    }
    float z[OC];
#pragma unroll
    for (int c = 0; c < OC; ++c) z[c] = b2s[c];
#pragma unroll
    for (int k = 0; k < HID; ++k) {
        float av = a[k];
#pragma unroll
        for (int c = 0; c < OC; ++c) z[c] += av * w2s[k * OC + c];
    }
    float m = z[0];
#pragma unroll
    for (int c = 1; c < OC; ++c) m = fmaxf(m, z[c]);
    float ssum = 0.f;
#pragma unroll
    for (int c = 0; c < OC; ++c) ssum += expf(z[c] - m);
    float lse = m + logf(ssum);
#pragma unroll
    for (int c = 0; c < OC; ++c) out[row * OC + c] = z[c] - lse;
}

extern "C" void kernel_launch(void* const* d_in, const int* in_sizes, int n_in,
                              void* d_out, int out_size, void* d_ws, size_t ws_size,
                              hipStream_t stream) {
    const float* x  = (const float*)d_in[0];
    const int*   ei = (const int*)d_in[1];
    const float* W1 = (const float*)d_in[2];
    const float* b1 = (const float*)d_in[3];
    const float* W2 = (const float*)d_in[4];
    const float* b2 = (const float*)d_in[5];
    float* out = (float*)d_out;

    const int* src = ei;       // edge_index[0]
    const int* dst = ei + NE;  // edge_index[1]

    char* ws = (char*)d_ws;
    size_t o = 0;
    int*   cursor = (int*)(ws + o);   o += (size_t)NB * CSTRIDE * 4;  // 100KB
    float* dis    = (float*)(ws + o); o += (size_t)NN * 4;            // 400KB
    int*   off    = (int*)(ws + o);   o += (size_t)NN * 4;            // 400KB
    int*   endv   = (int*)(ws + o);   o += (size_t)NN * 4;            // 400KB
    int*   bin    = (int*)(ws + o);   o += (size_t)NB * CAP * 4;      // 15.2MB
    float* bufA   = (float*)(ws + o); o += (size_t)NN * HID * 4;      // 6.4MB
    float* bufB   = (float*)(ws + o); o += (size_t)NN * HID * 4;      // 6.4MB

    dim3 B(256);
    int gE = (NE + 255) / 256;
    int gC = (NB * CSTRIDE + 255) / 256;
    int gG = (NN + 63) / 64;
    int gN = (NN + 255) / 256;

    k_zero_i<<<gC, B, 0, stream>>>(cursor, NB * CSTRIDE);
    k_bin<<<gE, B, 0, stream>>>(src, dst, cursor, bin);
    k_sort<<<NB, B, 0, stream>>>(bin, cursor, off, endv, dis);
    k_gemm1<<<NN / 16, B, 0, stream>>>(x, W1, dis, bufA);
    k_gather<<<gG, B, 0, stream>>>(bufA, dis, off, endv, bin, b1, bufB, 1);
    k_gather<<<gG, B, 0, stream>>>(bufB, dis, off, endv, bin, b2, bufA, 0);
    k_final<<<gN, B, 0, stream>>>(bufA, W2, b2, out);
}

// Round 5
// 203.465 us; speedup vs baseline: 4.4082x; 1.6344x over previous
//
#include <hip/hip_runtime.h>
#include <math.h>

#define NN 100000
#define NE 3200000
#define INC 128
#define HID 16
#define OC 40

#define NBK 391       // buckets of 256 dst-nodes: ceil(100000/256)
#define CAP 8960      // mean 8184 + ~8.5 sigma
#define CSTRIDE 16    // one 64B line per cursor
#define EB 8192       // edges per partition block
#define PBLK 391      // ceil(NE/EB)

__global__ void k_zero_i(int* __restrict__ p, int n) {
    int i = blockIdx.x * blockDim.x + threadIdx.x;
    if (i < n) p[i] = 0;
}

// Two-level partition: each block counting-sorts its 8192-edge chunk by dst
// bucket (dst>>8) in LDS, reserves per-bucket global ranges, flushes
// coalesced. Packed word = (dst&255)<<17 | src   (src < 2^17).
__global__ __launch_bounds__(512) void k_part(const int* __restrict__ src,
                                              const int* __restrict__ dst,
                                              int* __restrict__ cursor,
                                              int* __restrict__ bin) {
    __shared__ int hist[512];
    __shared__ int pref[512];
    __shared__ int lcur[512];
    __shared__ int gbase[512];
    __shared__ unsigned sorted[EB];  // 32KB
    __shared__ int tot_s;
    int t = threadIdx.x;
    int e0 = blockIdx.x * EB;
    int cnt = min(EB, NE - e0);
    hist[t] = 0;
    __syncthreads();
    // pass 1: histogram
    for (int i = t; i < cnt; i += 512) {
        unsigned d = (unsigned)dst[e0 + i];
        unsigned s = (unsigned)src[e0 + i];
        if (d < NN && s < NN) atomicAdd(&hist[d >> 8], 1);
    }
    __syncthreads();
    // inclusive scan over 512
    pref[t] = hist[t];
    __syncthreads();
    for (int d = 1; d < 512; d <<= 1) {
        int add = (t >= d) ? pref[t - d] : 0;
        __syncthreads();
        pref[t] += add;
        __syncthreads();
    }
    int lst = pref[t] - hist[t];  // exclusive
    lcur[t] = 0;
    pref[t] = lst;                // pref now holds lstart
    if (t == 511) tot_s = lst + hist[511];
    if (t < NBK) gbase[t] = atomicAdd(&cursor[t * CSTRIDE], hist[t]);
    __syncthreads();
    // pass 2: local scatter into sorted LDS (re-read edges, L2-hot)
    for (int i = t; i < cnt; i += 512) {
        unsigned d = (unsigned)dst[e0 + i];
        unsigned s = (unsigned)src[e0 + i];
        if (d < NN && s < NN) {
            int b = (int)(d >> 8);
            int p = atomicAdd(&lcur[b], 1);
            sorted[pref[b] + p] = ((d & 255u) << 17) | s;
        }
    }
    __syncthreads();
    // flush: lane-major, coalesced within runs; binary search bucket of i
    int tot = tot_s;
    for (int i = t; i < tot; i += 512) {
        unsigned w = sorted[i];
        int lo = 0, hi = NBK - 1;
        while (lo < hi) {
            int mid = (lo + hi + 1) >> 1;
            if (pref[mid] <= i) lo = mid; else hi = mid - 1;
        }
        int gp = gbase[lo] + (i - pref[lo]);
        if (gp < CAP) bin[lo * CAP + gp] = (int)w;
    }
}

// per-bucket counting sort by local dst (in place); emits off/end/dis
__global__ __launch_bounds__(256) void k_bsort(int* __restrict__ bin,
                                               const int* __restrict__ cursor,
                                               int* __restrict__ off,
                                               int* __restrict__ endv,
                                               float* __restrict__ dis) {
    __shared__ int hist[256];
    __shared__ int pref[256];
    __shared__ int lcur[256];
    __shared__ int sorted[CAP];  // 35.8KB
    int b = blockIdx.x, t = threadIdx.x;
    int cnt = cursor[b * CSTRIDE];
    if (cnt > CAP) cnt = CAP;
    int base = b * CAP;
    hist[t] = 0;
    __syncthreads();
    for (int i = t; i < cnt; i += 256) {
        unsigned w = (unsigned)bin[base + i];
        atomicAdd(&hist[w >> 17], 1);
    }
    __syncthreads();
    pref[t] = hist[t];
    __syncthreads();
    for (int d = 1; d < 256; d <<= 1) {
        int add = (t >= d) ? pref[t - d] : 0;
        __syncthreads();
        pref[t] += add;
        __syncthreads();
    }
    lcur[t] = pref[t] - hist[t];
    __syncthreads();
    for (int i = t; i < cnt; i += 256) {
        unsigned w = (unsigned)bin[base + i];
        int p = atomicAdd(&lcur[w >> 17], 1);
        sorted[p] = (int)(w & 0x1FFFF);
    }
    __syncthreads();
    for (int i = t; i < cnt; i += 256) bin[base + i] = sorted[i];
    int node = (b << 8) + t;
    if (node < NN) {
        off[node]  = base + pref[t] - hist[t];
        endv[node] = base + pref[t];
        dis[node]  = rsqrtf((float)(hist[t] + 1));  // +1 self-loop
    }
}

// g1 = dis[i] * (x @ W1)[i]
__global__ __launch_bounds__(256) void k_gemm1(const float* __restrict__ x,
                                               const float* __restrict__ W1,
                                               const float* __restrict__ dis,
                                               float* __restrict__ g1) {
    __shared__ float xs[16][INC + 1];
    __shared__ float ws[INC][HID];
    int t = threadIdx.x;
    int rowbase = blockIdx.x * 16;  // NN/16 = 6250 exact
#pragma unroll
    for (int i = 0; i < 8; ++i) {
        int idx = t + i * 256;
        xs[idx >> 7][idx & 127] = x[(long long)(rowbase)*INC + idx];
    }
#pragma unroll
    for (int i = 0; i < 8; ++i) {
        int idx = t + i * 256;
        ws[idx >> 4][idx & 15] = W1[idx];
    }
    __syncthreads();
    int r = t >> 4, c = t & 15;
    float acc = 0.f;
#pragma unroll
    for (int k = 0; k < INC; ++k) acc += xs[r][k] * ws[k][c];
    int row = rowbase + r;
    g1[row * HID + c] = dis[row] * acc;
}

// out[i] = di*(sum_{s in-edges} gin[s] + gin[i]);  mode1: relu(+bias)*di
__global__ __launch_bounds__(256) void k_gather(const float* __restrict__ gin,
                                                const float* __restrict__ dis,
                                                const int* __restrict__ off,
                                                const int* __restrict__ endv,
                                                const int* __restrict__ bin,
                                                const float* __restrict__ bias,
                                                float* __restrict__ outp, int mode) {
    int t = threadIdx.x;
    int node = blockIdx.x * 64 + (t >> 2);
    if (node >= NN) return;
    int c4 = t & 3;
    const float4* gv = (const float4*)gin;
    float4 acc = gv[node * 4 + c4];  // self contribution
    int j = off[node], end = endv[node];
    for (; j + 3 < end; j += 4) {
        int s0 = bin[j], s1 = bin[j + 1], s2 = bin[j + 2], s3 = bin[j + 3];
        float4 v0 = gv[s0 * 4 + c4];
        float4 v1 = gv[s1 * 4 + c4];
        float4 v2 = gv[s2 * 4 + c4];
        float4 v3 = gv[s3 * 4 + c4];
        acc.x += (v0.x + v1.x) + (v2.x + v3.x);
        acc.y += (v0.y + v1.y) + (v2.y + v3.y);
        acc.z += (v0.z + v1.z) + (v2.z + v3.z);
        acc.w += (v0.w + v1.w) + (v2.w + v3.w);
    }
    for (; j < end; ++j) {
        int s = bin[j];
        float4 v = gv[s * 4 + c4];
        acc.x += v.x; acc.y += v.y; acc.z += v.z; acc.w += v.w;
    }
    float di = dis[node];
    float4 val;
    val.x = di * acc.x; val.y = di * acc.y; val.z = di * acc.z; val.w = di * acc.w;
    if (mode) {
        val.x = fmaxf(val.x + bias[c4 * 4 + 0], 0.f) * di;
        val.y = fmaxf(val.y + bias[c4 * 4 + 1], 0.f) * di;
        val.z = fmaxf(val.z + bias[c4 * 4 + 2], 0.f) * di;
        val.w = fmaxf(val.w + bias[c4 * 4 + 3], 0.f) * di;
    }
    ((float4*)outp)[node * 4 + c4] = val;
}

// out[i] = log_softmax(in2[i] @ W2 + b2)
__global__ __launch_bounds__(256) void k_final(const float* __restrict__ in2,
                                               const float* __restrict__ W2,
                                               const float* __restrict__ b2,
                                               float* __restrict__ out) {
    __shared__ float w2s[HID * OC];
    __shared__ float b2s[OC];
    int t = threadIdx.x;
    for (int i = t; i < HID * OC; i += 256) w2s[i] = W2[i];
    if (t < OC) b2s[t] = b2[t];
    __syncthreads();
    int row = blockIdx.x * 256 + t;
    if (row >= NN) return;
    float a[HID];
    const float4* iv = (const float4*)(in2 + row * HID);
#pragma unroll
    for (int q = 0; q < 4; ++q) {
        float4 v = iv[q];
        a[q * 4 + 0] = v.x; a[q * 4 + 1] = v.y; a[q * 4 + 2] = v.z; a[q * 4 + 3] = v.w;
    }
    float z[OC];
#pragma unroll
    for (int c = 0; c < OC; ++c) z[c] = b2s[c];
#pragma unroll
    for (int k = 0; k < HID; ++k) {
        float av = a[k];
#pragma unroll
        for (int c = 0; c < OC; ++c) z[c] += av * w2s[k * OC + c];
    }
    float m = z[0];
#pragma unroll
    for (int c = 1; c < OC; ++c) m = fmaxf(m, z[c]);
    float ssum = 0.f;
#pragma unroll
    for (int c = 0; c < OC; ++c) ssum += expf(z[c] - m);
    float lse = m + logf(ssum);
#pragma unroll
    for (int c = 0; c < OC; ++c) out[row * OC + c] = z[c] - lse;
}

extern "C" void kernel_launch(void* const* d_in, const int* in_sizes, int n_in,
                              void* d_out, int out_size, void* d_ws, size_t ws_size,
                              hipStream_t stream) {
    const float* x  = (const float*)d_in[0];
    const int*   ei = (const int*)d_in[1];
    const float* W1 = (const float*)d_in[2];
    const float* b1 = (const float*)d_in[3];
    const float* W2 = (const float*)d_in[4];
    const float* b2 = (const float*)d_in[5];
    float* out = (float*)d_out;

    const int* src = ei;       // edge_index[0]
    const int* dst = ei + NE;  // edge_index[1]

    char* ws = (char*)d_ws;
    size_t o = 0;
    int*   cursor = (int*)(ws + o);   o += (size_t)NBK * CSTRIDE * 4;  // 25KB
    float* dis    = (float*)(ws + o); o += (size_t)NN * 4;             // 400KB
    int*   off    = (int*)(ws + o);   o += (size_t)NN * 4;             // 400KB
    int*   endv   = (int*)(ws + o);   o += (size_t)NN * 4;             // 400KB
    int*   bin    = (int*)(ws + o);   o += (size_t)NBK * CAP * 4;      // 14.0MB
    float* bufA   = (float*)(ws + o); o += (size_t)NN * HID * 4;       // 6.4MB
    float* bufB   = (float*)(ws + o); o += (size_t)NN * HID * 4;       // 6.4MB

    dim3 B(256);
    int gC = (NBK * CSTRIDE + 255) / 256;
    int gG = (NN + 63) / 64;
    int gN = (NN + 255) / 256;

    k_zero_i<<<gC, B, 0, stream>>>(cursor, NBK * CSTRIDE);
    k_part<<<PBLK, 512, 0, stream>>>(src, dst, cursor, bin);
    k_bsort<<<NBK, B, 0, stream>>>(bin, cursor, off, endv, dis);
    k_gemm1<<<NN / 16, B, 0, stream>>>(x, W1, dis, bufA);
    k_gather<<<gG, B, 0, stream>>>(bufA, dis, off, endv, bin, b1, bufB, 1);
    k_gather<<<gG, B, 0, stream>>>(bufB, dis, off, endv, bin, b2, bufA, 0);
    k_final<<<gN, B, 0, stream>>>(bufA, W2, b2, out);
}

// Round 6
// 169.631 us; speedup vs baseline: 5.2874x; 1.1995x over previous
//
#include <hip/hip_runtime.h>
#include <math.h>

#define NN 100000
#define NE 3200000
#define INC 128
#define HID 16
#define OC 40

#define NBK 391       // buckets of 256 dst-nodes: ceil(100000/256)
#define CAP 8960      // mean 8184 + ~8.5 sigma
#define CSTRIDE 16    // one 64B line per cursor
#define EB 8192       // edges per partition block
#define PBLK 391      // ceil(NE/EB)

__device__ __forceinline__ unsigned bf16r(float f) {  // RNE fp32->bf16 (as u16)
    unsigned u = __float_as_uint(f);
    return (u + 0x7FFFu + ((u >> 16) & 1u)) >> 16;
}
__device__ __forceinline__ unsigned packbf(float a, float b) {
    return bf16r(a) | (bf16r(b) << 16);
}
__device__ __forceinline__ float bflo(unsigned u) { return __uint_as_float(u << 16); }
__device__ __forceinline__ float bfhi(unsigned u) { return __uint_as_float(u & 0xFFFF0000u); }

__global__ void k_zero_i(int* __restrict__ p, int n) {
    int i = blockIdx.x * blockDim.x + threadIdx.x;
    if (i < n) p[i] = 0;
}

// Two-level partition: each block counting-sorts its 8192-edge chunk by dst
// bucket (dst>>8) in LDS, reserves per-bucket global ranges, flushes
// coalesced. Packed word = (dst&255)<<17 | src   (src < 2^17).
__global__ __launch_bounds__(512) void k_part(const int* __restrict__ src,
                                              const int* __restrict__ dst,
                                              int* __restrict__ cursor,
                                              int* __restrict__ bin) {
    __shared__ int hist[512];
    __shared__ int pref[512];
    __shared__ int lcur[512];
    __shared__ int gbase[512];
    __shared__ unsigned sorted[EB];  // 32KB
    __shared__ int tot_s;
    int t = threadIdx.x;
    int e0 = blockIdx.x * EB;
    int cnt = min(EB, NE - e0);
    hist[t] = 0;
    __syncthreads();
    for (int i = t; i < cnt; i += 512) {
        unsigned d = (unsigned)dst[e0 + i];
        unsigned s = (unsigned)src[e0 + i];
        if (d < NN && s < NN) atomicAdd(&hist[d >> 8], 1);
    }
    __syncthreads();
    pref[t] = hist[t];
    __syncthreads();
    for (int d = 1; d < 512; d <<= 1) {
        int add = (t >= d) ? pref[t - d] : 0;
        __syncthreads();
        pref[t] += add;
        __syncthreads();
    }
    int lst = pref[t] - hist[t];  // exclusive
    lcur[t] = 0;
    pref[t] = lst;
    if (t == 511) tot_s = lst + hist[511];
    if (t < NBK) gbase[t] = atomicAdd(&cursor[t * CSTRIDE], hist[t]);
    __syncthreads();
    for (int i = t; i < cnt; i += 512) {
        unsigned d = (unsigned)dst[e0 + i];
        unsigned s = (unsigned)src[e0 + i];
        if (d < NN && s < NN) {
            int b = (int)(d >> 8);
            int p = atomicAdd(&lcur[b], 1);
            sorted[pref[b] + p] = ((d & 255u) << 17) | s;
        }
    }
    __syncthreads();
    int tot = tot_s;
    for (int i = t; i < tot; i += 512) {
        unsigned w = sorted[i];
        int lo = 0, hi = NBK - 1;
        while (lo < hi) {
            int mid = (lo + hi + 1) >> 1;
            if (pref[mid] <= i) lo = mid; else hi = mid - 1;
        }
        int gp = gbase[lo] + (i - pref[lo]);
        if (gp < CAP) bin[lo * CAP + gp] = (int)w;
    }
}

// per-bucket counting sort by local dst (in place); emits off/end/dis
__global__ __launch_bounds__(256) void k_bsort(int* __restrict__ bin,
                                               const int* __restrict__ cursor,
                                               int* __restrict__ off,
                                               int* __restrict__ endv,
                                               float* __restrict__ dis) {
    __shared__ int hist[256];
    __shared__ int pref[256];
    __shared__ int lcur[256];
    __shared__ int sorted[CAP];  // 35.8KB
    int b = blockIdx.x, t = threadIdx.x;
    int cnt = cursor[b * CSTRIDE];
    if (cnt > CAP) cnt = CAP;
    int base = b * CAP;
    hist[t] = 0;
    __syncthreads();
    for (int i = t; i < cnt; i += 256) {
        unsigned w = (unsigned)bin[base + i];
        atomicAdd(&hist[w >> 17], 1);
    }
    __syncthreads();
    pref[t] = hist[t];
    __syncthreads();
    for (int d = 1; d < 256; d <<= 1) {
        int add = (t >= d) ? pref[t - d] : 0;
        __syncthreads();
        pref[t] += add;
        __syncthreads();
    }
    lcur[t] = pref[t] - hist[t];
    __syncthreads();
    for (int i = t; i < cnt; i += 256) {
        unsigned w = (unsigned)bin[base + i];
        int p = atomicAdd(&lcur[w >> 17], 1);
        sorted[p] = (int)(w & 0x1FFFF);
    }
    __syncthreads();
    for (int i = t; i < cnt; i += 256) bin[base + i] = sorted[i];
    int node = (b << 8) + t;
    if (node < NN) {
        off[node]  = base + pref[t] - hist[t];
        endv[node] = base + pref[t];
        dis[node]  = rsqrtf((float)(hist[t] + 1));  // +1 self-loop
    }
}

// g1[bf16] = dis[i] * (x @ W1)[i] ; packed 2 channels per uint, 8 uints/row
__global__ __launch_bounds__(256) void k_gemm1(const float* __restrict__ x,
                                               const float* __restrict__ W1,
                                               const float* __restrict__ dis,
                                               unsigned* __restrict__ g1) {
    __shared__ float xs[16][INC + 1];
    __shared__ float ws[INC][HID];
    __shared__ float accs[16][17];
    int t = threadIdx.x;
    int rowbase = blockIdx.x * 16;  // NN/16 = 6250 exact
#pragma unroll
    for (int i = 0; i < 8; ++i) {
        int idx = t + i * 256;
        xs[idx >> 7][idx & 127] = x[(long long)(rowbase)*INC + idx];
    }
#pragma unroll
    for (int i = 0; i < 8; ++i) {
        int idx = t + i * 256;
        ws[idx >> 4][idx & 15] = W1[idx];
    }
    __syncthreads();
    int r = t >> 4, c = t & 15;
    float acc = 0.f;
#pragma unroll
    for (int k = 0; k < INC; ++k) acc += xs[r][k] * ws[k][c];
    accs[r][c] = dis[rowbase + r] * acc;
    __syncthreads();
    if (t < 128) {
        int row = t >> 3, p = t & 7;
        g1[(rowbase + row) * 8 + p] = packbf(accs[row][2 * p], accs[row][2 * p + 1]);
    }
}

// out[i] = di*(sum_{s} g[s] + g[i]);  mode1: bf16 out = relu(+bias)*di ; mode0: fp32 out
// 4 lanes per node, uint2 (4 bf16 ch) per lane
__global__ __launch_bounds__(256) void k_gather(const unsigned* __restrict__ gin,
                                                const float* __restrict__ dis,
                                                const int* __restrict__ off,
                                                const int* __restrict__ endv,
                                                const int* __restrict__ bin,
                                                const float* __restrict__ bias,
                                                unsigned* __restrict__ outbf,
                                                float* __restrict__ outf, int mode) {
    int t = threadIdx.x;
    int node = blockIdx.x * 64 + (t >> 2);
    if (node >= NN) return;
    int c4 = t & 3;
    const uint2* gv = (const uint2*)gin;
    uint2 u = gv[node * 4 + c4];  // self contribution
    float a0 = bflo(u.x), a1 = bfhi(u.x), a2 = bflo(u.y), a3 = bfhi(u.y);
    int j = off[node], end = endv[node];
    for (; j + 3 < end; j += 4) {
        int s0 = bin[j], s1 = bin[j + 1], s2 = bin[j + 2], s3 = bin[j + 3];
        uint2 u0 = gv[s0 * 4 + c4];
        uint2 u1 = gv[s1 * 4 + c4];
        uint2 u2 = gv[s2 * 4 + c4];
        uint2 u3 = gv[s3 * 4 + c4];
        a0 += (bflo(u0.x) + bflo(u1.x)) + (bflo(u2.x) + bflo(u3.x));
        a1 += (bfhi(u0.x) + bfhi(u1.x)) + (bfhi(u2.x) + bfhi(u3.x));
        a2 += (bflo(u0.y) + bflo(u1.y)) + (bflo(u2.y) + bflo(u3.y));
        a3 += (bfhi(u0.y) + bfhi(u1.y)) + (bfhi(u2.y) + bfhi(u3.y));
    }
    for (; j < end; ++j) {
        uint2 uu = gv[bin[j] * 4 + c4];
        a0 += bflo(uu.x); a1 += bfhi(uu.x); a2 += bflo(uu.y); a3 += bfhi(uu.y);
    }
    float di = dis[node];
    a0 *= di; a1 *= di; a2 *= di; a3 *= di;
    if (mode) {
        a0 = fmaxf(a0 + bias[c4 * 4 + 0], 0.f) * di;
        a1 = fmaxf(a1 + bias[c4 * 4 + 1], 0.f) * di;
        a2 = fmaxf(a2 + bias[c4 * 4 + 2], 0.f) * di;
        a3 = fmaxf(a3 + bias[c4 * 4 + 3], 0.f) * di;
        uint2 o; o.x = packbf(a0, a1); o.y = packbf(a2, a3);
        ((uint2*)outbf)[node * 4 + c4] = o;
    } else {
        float4 v; v.x = a0; v.y = a1; v.z = a2; v.w = a3;
        ((float4*)outf)[node * 4 + c4] = v;
    }
}

// out[i] = log_softmax(in2[i] @ W2 + b2)
__global__ __launch_bounds__(256) void k_final(const float* __restrict__ in2,
                                               const float* __restrict__ W2,
                                               const float* __restrict__ b2,
                                               float* __restrict__ out) {
    __shared__ float w2s[HID * OC];
    __shared__ float b2s[OC];
    int t = threadIdx.x;
    for (int i = t; i < HID * OC; i += 256) w2s[i] = W2[i];
    if (t < OC) b2s[t] = b2[t];
    __syncthreads();
    int row = blockIdx.x * 256 + t;
    if (row >= NN) return;
    float a[HID];
    const float4* iv = (const float4*)(in2 + row * HID);
#pragma unroll
    for (int q = 0; q < 4; ++q) {
        float4 v = iv[q];
        a[q * 4 + 0] = v.x; a[q * 4 + 1] = v.y; a[q * 4 + 2] = v.z; a[q * 4 + 3] = v.w;
    }
    float z[OC];
#pragma unroll
    for (int c = 0; c < OC; ++c) z[c] = b2s[c];
#pragma unroll
    for (int k = 0; k < HID; ++k) {
        float av = a[k];
#pragma unroll
        for (int c = 0; c < OC; ++c) z[c] += av * w2s[k * OC + c];
    }
    float m = z[0];
#pragma unroll
    for (int c = 1; c < OC; ++c) m = fmaxf(m, z[c]);
    float ssum = 0.f;
#pragma unroll
    for (int c = 0; c < OC; ++c) ssum += expf(z[c] - m);
    float lse = m + logf(ssum);
#pragma unroll
    for (int c = 0; c < OC; ++c) out[row * OC + c] = z[c] - lse;
}

extern "C" void kernel_launch(void* const* d_in, const int* in_sizes, int n_in,
                              void* d_out, int out_size, void* d_ws, size_t ws_size,
                              hipStream_t stream) {
    const float* x  = (const float*)d_in[0];
    const int*   ei = (const int*)d_in[1];
    const float* W1 = (const float*)d_in[2];
    const float* b1 = (const float*)d_in[3];
    const float* W2 = (const float*)d_in[4];
    const float* b2 = (const float*)d_in[5];
    float* out = (float*)d_out;

    const int* src = ei;       // edge_index[0]
    const int* dst = ei + NE;  // edge_index[1]

    char* ws = (char*)d_ws;
    size_t o = 0;
    int*      cursor = (int*)(ws + o);      o += (size_t)NBK * CSTRIDE * 4;  // 25KB
    float*    dis    = (float*)(ws + o);    o += (size_t)NN * 4;             // 400KB
    int*      off    = (int*)(ws + o);      o += (size_t)NN * 4;             // 400KB
    int*      endv   = (int*)(ws + o);      o += (size_t)NN * 4;             // 400KB
    int*      bin    = (int*)(ws + o);      o += (size_t)NBK * CAP * 4;      // 14.0MB
    unsigned* gbf1   = (unsigned*)(ws + o); o += (size_t)NN * 8 * 4;         // 3.2MB
    unsigned* gbf2   = (unsigned*)(ws + o); o += (size_t)NN * 8 * 4;         // 3.2MB
    float*    in2    = (float*)(ws + o);    o += (size_t)NN * HID * 4;       // 6.4MB

    dim3 B(256);
    int gC = (NBK * CSTRIDE + 255) / 256;
    int gG = (NN + 63) / 64;
    int gN = (NN + 255) / 256;

    k_zero_i<<<gC, B, 0, stream>>>(cursor, NBK * CSTRIDE);
    k_part<<<PBLK, 512, 0, stream>>>(src, dst, cursor, bin);
    k_bsort<<<NBK, B, 0, stream>>>(bin, cursor, off, endv, dis);
    k_gemm1<<<NN / 16, B, 0, stream>>>(x, W1, dis, gbf1);
    k_gather<<<gG, B, 0, stream>>>(gbf1, dis, off, endv, bin, b1, gbf2, in2, 1);
    k_gather<<<gG, B, 0, stream>>>(gbf2, dis, off, endv, bin, b2, gbf1, in2, 0);
    k_final<<<gN, B, 0, stream>>>(in2, W2, b2, out);
}

// Round 7
// 165.143 us; speedup vs baseline: 5.4311x; 1.0272x over previous
//
#include <hip/hip_runtime.h>
#include <math.h>

#define NN 100000
#define NE 3200000
#define INC 128
#define HID 16
#define OC 40

#define NBK 391       // buckets of 256 dst-nodes: ceil(100000/256)
#define CAP 8960      // mean 8184 + ~8.5 sigma
#define CSTRIDE 16    // one 64B line per cursor
#define EB 4096       // edges per partition block
#define PBLK 782      // ceil(NE/EB)

__device__ __forceinline__ unsigned bf16r(float f) {  // RNE fp32->bf16 (as u16)
    unsigned u = __float_as_uint(f);
    return (u + 0x7FFFu + ((u >> 16) & 1u)) >> 16;
}
__device__ __forceinline__ unsigned packbf(float a, float b) {
    return bf16r(a) | (bf16r(b) << 16);
}
__device__ __forceinline__ float bflo(unsigned u) { return __uint_as_float(u << 16); }
__device__ __forceinline__ float bfhi(unsigned u) { return __uint_as_float(u & 0xFFFF0000u); }

__global__ void k_zero_i(int* __restrict__ p, int n) {
    int i = blockIdx.x * blockDim.x + threadIdx.x;
    if (i < n) p[i] = 0;
}

// Two-level partition: each block counting-sorts its 4096-edge chunk by dst
// bucket (dst>>8) in LDS, reserves per-bucket global ranges, flushes
// coalesced. Packed word = (dst&255)<<17 | src   (src < 2^17).
__global__ __launch_bounds__(512) void k_part(const int* __restrict__ src,
                                              const int* __restrict__ dst,
                                              int* __restrict__ cursor,
                                              int* __restrict__ bin) {
    __shared__ int hist[512];
    __shared__ int pref[512];
    __shared__ int lcur[512];
    __shared__ int gbase[512];
    __shared__ unsigned sorted[EB];  // 16KB
    __shared__ int tot_s;
    int t = threadIdx.x;
    int e0 = blockIdx.x * EB;
    int cnt = min(EB, NE - e0);
    hist[t] = 0;
    __syncthreads();
    for (int i = t; i < cnt; i += 512) {
        unsigned d = (unsigned)dst[e0 + i];
        unsigned s = (unsigned)src[e0 + i];
        if (d < NN && s < NN) atomicAdd(&hist[d >> 8], 1);
    }
    __syncthreads();
    pref[t] = hist[t];
    __syncthreads();
    for (int d = 1; d < 512; d <<= 1) {
        int add = (t >= d) ? pref[t - d] : 0;
        __syncthreads();
        pref[t] += add;
        __syncthreads();
    }
    int lst = pref[t] - hist[t];  // exclusive
    lcur[t] = 0;
    pref[t] = lst;
    if (t == 511) tot_s = lst + hist[511];
    if (t < NBK) gbase[t] = atomicAdd(&cursor[t * CSTRIDE], hist[t]);
    __syncthreads();
    for (int i = t; i < cnt; i += 512) {
        unsigned d = (unsigned)dst[e0 + i];
        unsigned s = (unsigned)src[e0 + i];
        if (d < NN && s < NN) {
            int b = (int)(d >> 8);
            int p = atomicAdd(&lcur[b], 1);
            sorted[pref[b] + p] = ((d & 255u) << 17) | s;
        }
    }
    __syncthreads();
    int tot = tot_s;
    for (int i = t; i < tot; i += 512) {
        unsigned w = sorted[i];
        int lo = 0, hi = NBK - 1;
        while (lo < hi) {
            int mid = (lo + hi + 1) >> 1;
            if (pref[mid] <= i) lo = mid; else hi = mid - 1;
        }
        int gp = gbase[lo] + (i - pref[lo]);
        if (gp < CAP) bin[lo * CAP + gp] = (int)w;
    }
}

// per-bucket counting sort by local dst (in place); emits off/end/dis
__global__ __launch_bounds__(512) void k_bsort(int* __restrict__ bin,
                                               const int* __restrict__ cursor,
                                               int* __restrict__ off,
                                               int* __restrict__ endv,
                                               float* __restrict__ dis) {
    __shared__ int hist[256];
    __shared__ int pref[256];
    __shared__ int lcur[256];
    __shared__ int sorted[CAP];  // 35.8KB
    int b = blockIdx.x, t = threadIdx.x;
    int cnt = cursor[b * CSTRIDE];
    if (cnt > CAP) cnt = CAP;
    int base = b * CAP;
    if (t < 256) hist[t] = 0;
    __syncthreads();
    for (int i = t; i < cnt; i += 512) {
        unsigned w = (unsigned)bin[base + i];
        atomicAdd(&hist[w >> 17], 1);
    }
    __syncthreads();
    if (t < 256) pref[t] = hist[t];
    __syncthreads();
    for (int d = 1; d < 256; d <<= 1) {
        int add = (t >= d && t < 256) ? pref[t - d] : 0;
        __syncthreads();
        if (t < 256) pref[t] += add;
        __syncthreads();
    }
    if (t < 256) lcur[t] = pref[t] - hist[t];
    __syncthreads();
    for (int i = t; i < cnt; i += 512) {
        unsigned w = (unsigned)bin[base + i];
        int p = atomicAdd(&lcur[w >> 17], 1);
        sorted[p] = (int)(w & 0x1FFFF);
    }
    __syncthreads();
    for (int i = t; i < cnt; i += 512) bin[base + i] = sorted[i];
    if (t < 256) {
        int node = (b << 8) + t;
        if (node < NN) {
            off[node]  = base + pref[t] - hist[t];
            endv[node] = base + pref[t];
            dis[node]  = rsqrtf((float)(hist[t] + 1));  // +1 self-loop
        }
    }
}

// g1[bf16] = dis[i] * (x @ W1)[i] ; packed 2 channels per uint, 8 uints/row
__global__ __launch_bounds__(256) void k_gemm1(const float* __restrict__ x,
                                               const float* __restrict__ W1,
                                               const float* __restrict__ dis,
                                               unsigned* __restrict__ g1) {
    __shared__ float xs[16][INC + 1];
    __shared__ float ws[INC][HID];
    __shared__ float accs[16][17];
    int t = threadIdx.x;
    int rowbase = blockIdx.x * 16;  // NN/16 = 6250 exact
#pragma unroll
    for (int i = 0; i < 8; ++i) {
        int idx = t + i * 256;
        xs[idx >> 7][idx & 127] = x[(long long)(rowbase)*INC + idx];
    }
#pragma unroll
    for (int i = 0; i < 8; ++i) {
        int idx = t + i * 256;
        ws[idx >> 4][idx & 15] = W1[idx];
    }
    __syncthreads();
    int r = t >> 4, c = t & 15;
    float acc = 0.f;
#pragma unroll
    for (int k = 0; k < INC; ++k) acc += xs[r][k] * ws[k][c];
    accs[r][c] = dis[rowbase + r] * acc;
    __syncthreads();
    if (t < 128) {
        int row = t >> 3, p = t & 7;
        g1[(rowbase + row) * 8 + p] = packbf(accs[row][2 * p], accs[row][2 * p + 1]);
    }
}

// out[i] = di*(sum_{s} g[s] + g[i]);  mode1: bf16 out = relu(+bias)*di ; mode0: fp32 out
// 4 lanes per node, uint2 (4 bf16 ch) per lane
__global__ __launch_bounds__(256) void k_gather(const unsigned* __restrict__ gin,
                                                const float* __restrict__ dis,
                                                const int* __restrict__ off,
                                                const int* __restrict__ endv,
                                                const int* __restrict__ bin,
                                                const float* __restrict__ bias,
                                                unsigned* __restrict__ outbf,
                                                float* __restrict__ outf, int mode) {
    int t = threadIdx.x;
    int node = blockIdx.x * 64 + (t >> 2);
    if (node >= NN) return;
    int c4 = t & 3;
    const uint2* gv = (const uint2*)gin;
    uint2 u = gv[node * 4 + c4];  // self contribution
    float a0 = bflo(u.x), a1 = bfhi(u.x), a2 = bflo(u.y), a3 = bfhi(u.y);
    int j = off[node], end = endv[node];
    for (; j + 3 < end; j += 4) {
        int s0 = bin[j], s1 = bin[j + 1], s2 = bin[j + 2], s3 = bin[j + 3];
        uint2 u0 = gv[s0 * 4 + c4];
        uint2 u1 = gv[s1 * 4 + c4];
        uint2 u2 = gv[s2 * 4 + c4];
        uint2 u3 = gv[s3 * 4 + c4];
        a0 += (bflo(u0.x) + bflo(u1.x)) + (bflo(u2.x) + bflo(u3.x));
        a1 += (bfhi(u0.x) + bfhi(u1.x)) + (bfhi(u2.x) + bfhi(u3.x));
        a2 += (bflo(u0.y) + bflo(u1.y)) + (bflo(u2.y) + bflo(u3.y));
        a3 += (bfhi(u0.y) + bfhi(u1.y)) + (bfhi(u2.y) + bfhi(u3.y));
    }
    for (; j < end; ++j) {
        uint2 uu = gv[bin[j] * 4 + c4];
        a0 += bflo(uu.x); a1 += bfhi(uu.x); a2 += bflo(uu.y); a3 += bfhi(uu.y);
    }
    float di = dis[node];
    a0 *= di; a1 *= di; a2 *= di; a3 *= di;
    if (mode) {
        a0 = fmaxf(a0 + bias[c4 * 4 + 0], 0.f) * di;
        a1 = fmaxf(a1 + bias[c4 * 4 + 1], 0.f) * di;
        a2 = fmaxf(a2 + bias[c4 * 4 + 2], 0.f) * di;
        a3 = fmaxf(a3 + bias[c4 * 4 + 3], 0.f) * di;
        uint2 o; o.x = packbf(a0, a1); o.y = packbf(a2, a3);
        ((uint2*)outbf)[node * 4 + c4] = o;
    } else {
        float4 v; v.x = a0; v.y = a1; v.z = a2; v.w = a3;
        ((float4*)outf)[node * 4 + c4] = v;
    }
}

// out[i] = log_softmax(in2[i] @ W2 + b2)
__global__ __launch_bounds__(256) void k_final(const float* __restrict__ in2,
                                               const float* __restrict__ W2,
                                               const float* __restrict__ b2,
                                               float* __restrict__ out) {
    __shared__ float w2s[HID * OC];
    __shared__ float b2s[OC];
    int t = threadIdx.x;
    for (int i = t; i < HID * OC; i += 256) w2s[i] = W2[i];
    if (t < OC) b2s[t] = b2[t];
    __syncthreads();
    int row = blockIdx.x * 256 + t;
    if (row >= NN) return;
    float a[HID];
    const float4* iv = (const float4*)(in2 + row * HID);
#pragma unroll
    for (int q = 0; q < 4; ++q) {
        float4 v = iv[q];
        a[q * 4 + 0] = v.x; a[q * 4 + 1] = v.y; a[q * 4 + 2] = v.z; a[q * 4 + 3] = v.w;
    }
    float z[OC];
#pragma unroll
    for (int c = 0; c < OC; ++c) z[c] = b2s[c];
#pragma unroll
    for (int k = 0; k < HID; ++k) {
        float av = a[k];
#pragma unroll
        for (int c = 0; c < OC; ++c) z[c] += av * w2s[k * OC + c];
    }
    float m = z[0];
#pragma unroll
    for (int c = 1; c < OC; ++c) m = fmaxf(m, z[c]);
    float ssum = 0.f;
#pragma unroll
    for (int c = 0; c < OC; ++c) ssum += expf(z[c] - m);
    float lse = m + logf(ssum);
#pragma unroll
    for (int c = 0; c < OC; ++c) out[row * OC + c] = z[c] - lse;
}

extern "C" void kernel_launch(void* const* d_in, const int* in_sizes, int n_in,
                              void* d_out, int out_size, void* d_ws, size_t ws_size,
                              hipStream_t stream) {
    const float* x  = (const float*)d_in[0];
    const int*   ei = (const int*)d_in[1];
    const float* W1 = (const float*)d_in[2];
    const float* b1 = (const float*)d_in[3];
    const float* W2 = (const float*)d_in[4];
    const float* b2 = (const float*)d_in[5];
    float* out = (float*)d_out;

    const int* src = ei;       // edge_index[0]
    const int* dst = ei + NE;  // edge_index[1]

    char* ws = (char*)d_ws;
    size_t o = 0;
    int*      cursor = (int*)(ws + o);      o += (size_t)NBK * CSTRIDE * 4;  // 25KB
    float*    dis    = (float*)(ws + o);    o += (size_t)NN * 4;             // 400KB
    int*      off    = (int*)(ws + o);      o += (size_t)NN * 4;             // 400KB
    int*      endv   = (int*)(ws + o);      o += (size_t)NN * 4;             // 400KB
    int*      bin    = (int*)(ws + o);      o += (size_t)NBK * CAP * 4;      // 14.0MB
    unsigned* gbf1   = (unsigned*)(ws + o); o += (size_t)NN * 8 * 4;         // 3.2MB
    unsigned* gbf2   = (unsigned*)(ws + o); o += (size_t)NN * 8 * 4;         // 3.2MB
    float*    in2    = (float*)(ws + o);    o += (size_t)NN * HID * 4;       // 6.4MB

    dim3 B(256);
    int gC = (NBK * CSTRIDE + 255) / 256;
    int gG = (NN + 63) / 64;
    int gN = (NN + 255) / 256;

    k_zero_i<<<gC, B, 0, stream>>>(cursor, NBK * CSTRIDE);
    k_part<<<PBLK, 512, 0, stream>>>(src, dst, cursor, bin);
    k_bsort<<<NBK, 512, 0, stream>>>(bin, cursor, off, endv, dis);
    k_gemm1<<<NN / 16, B, 0, stream>>>(x, W1, dis, gbf1);
    k_gather<<<gG, B, 0, stream>>>(gbf1, dis, off, endv, bin, b1, gbf2, in2, 1);
    k_gather<<<gG, B, 0, stream>>>(gbf2, dis, off, endv, bin, b2, gbf1, in2, 0);
    k_final<<<gN, B, 0, stream>>>(in2, W2, b2, out);
}

// Round 8
// 149.427 us; speedup vs baseline: 6.0024x; 1.1052x over previous
//
#include <hip/hip_runtime.h>
#include <math.h>

#define NN 100000
#define NE 3200000
#define INC 128
#define HID 16
#define OC 40

#define NBK 391       // buckets of 256 dst-nodes: ceil(100000/256)
#define CAP 8960      // mean 8184 + ~8.5 sigma
#define CSTRIDE 16    // one 64B line per cursor
#define EB 4096       // edges per partition block
#define PBLK 782      // ceil(NE/EB)

__device__ __forceinline__ unsigned bf16r(float f) {  // RNE fp32->bf16 (as u16)
    unsigned u = __float_as_uint(f);
    return (u + 0x7FFFu + ((u >> 16) & 1u)) >> 16;
}
__device__ __forceinline__ unsigned packbf(float a, float b) {
    return bf16r(a) | (bf16r(b) << 16);
}
__device__ __forceinline__ float bflo(unsigned u) { return __uint_as_float(u << 16); }
__device__ __forceinline__ float bfhi(unsigned u) { return __uint_as_float(u & 0xFFFF0000u); }

__global__ void k_zero_i(int* __restrict__ p, int n) {
    int i = blockIdx.x * blockDim.x + threadIdx.x;
    if (i < n) p[i] = 0;
}

// Two-level partition: per-block LDS counting sort of a 4096-edge chunk by
// dst bucket (dst>>8); coalesced flush via recorded bucket ids (no search).
// Packed word = (dst&255)<<17 | src   (src < 2^17).
__global__ __launch_bounds__(512) void k_part(const int* __restrict__ src,
                                              const int* __restrict__ dst,
                                              int* __restrict__ cursor,
                                              int* __restrict__ bin) {
    __shared__ int hist[512];
    __shared__ int pref[512];
    __shared__ int lcur[512];
    __shared__ int gbase[512];
    __shared__ unsigned sorted[EB];         // 16KB
    __shared__ unsigned short sortedb[EB];  // 8KB: bucket id per output slot
    __shared__ int tot_s;
    int t = threadIdx.x;
    int e0 = blockIdx.x * EB;
    int cnt = min(EB, NE - e0);
    hist[t] = 0;
    __syncthreads();
    for (int i = t; i < cnt; i += 512) {
        unsigned d = (unsigned)dst[e0 + i];
        unsigned s = (unsigned)src[e0 + i];
        if (d < NN && s < NN) atomicAdd(&hist[d >> 8], 1);
    }
    __syncthreads();
    pref[t] = hist[t];
    __syncthreads();
    for (int d = 1; d < 512; d <<= 1) {
        int add = (t >= d) ? pref[t - d] : 0;
        __syncthreads();
        pref[t] += add;
        __syncthreads();
    }
    int lst = pref[t] - hist[t];  // exclusive
    lcur[t] = 0;
    pref[t] = lst;
    if (t == 511) tot_s = lst + hist[511];
    if (t < NBK) gbase[t] = atomicAdd(&cursor[t * CSTRIDE], hist[t]);
    __syncthreads();
    for (int i = t; i < cnt; i += 512) {
        unsigned d = (unsigned)dst[e0 + i];
        unsigned s = (unsigned)src[e0 + i];
        if (d < NN && s < NN) {
            int b = (int)(d >> 8);
            int p = atomicAdd(&lcur[b], 1);
            int idx = pref[b] + p;
            sorted[idx] = ((d & 255u) << 17) | s;
            sortedb[idx] = (unsigned short)b;
        }
    }
    __syncthreads();
    int tot = tot_s;
    for (int i = t; i < tot; i += 512) {
        int b = sortedb[i];
        int gp = gbase[b] + (i - pref[b]);
        if (gp < CAP) bin[b * CAP + gp] = (int)sorted[i];
    }
}

// per-bucket counting sort by local dst (in place); emits off/end/dis
__global__ __launch_bounds__(512) void k_bsort(int* __restrict__ bin,
                                               const int* __restrict__ cursor,
                                               int* __restrict__ off,
                                               int* __restrict__ endv,
                                               float* __restrict__ dis) {
    __shared__ int hist[256];
    __shared__ int pref[256];
    __shared__ int lcur[256];
    __shared__ int sorted[CAP];  // 35.8KB
    int b = blockIdx.x, t = threadIdx.x;
    int cnt = cursor[b * CSTRIDE];
    if (cnt > CAP) cnt = CAP;
    int base = b * CAP;
    if (t < 256) hist[t] = 0;
    __syncthreads();
    for (int i = t; i < cnt; i += 512) {
        unsigned w = (unsigned)bin[base + i];
        atomicAdd(&hist[w >> 17], 1);
    }
    __syncthreads();
    if (t < 256) pref[t] = hist[t];
    __syncthreads();
    for (int d = 1; d < 256; d <<= 1) {
        int add = (t >= d && t < 256) ? pref[t - d] : 0;
        __syncthreads();
        if (t < 256) pref[t] += add;
        __syncthreads();
    }
    if (t < 256) lcur[t] = pref[t] - hist[t];
    __syncthreads();
    for (int i = t; i < cnt; i += 512) {
        unsigned w = (unsigned)bin[base + i];
        int p = atomicAdd(&lcur[w >> 17], 1);
        sorted[p] = (int)(w & 0x1FFFF);
    }
    __syncthreads();
    for (int i = t; i < cnt; i += 512) bin[base + i] = sorted[i];
    if (t < 256) {
        int node = (b << 8) + t;
        if (node < NN) {
            off[node]  = base + pref[t] - hist[t];
            endv[node] = base + pref[t];
            dis[node]  = rsqrtf((float)(hist[t] + 1));  // +1 self-loop
        }
    }
}

// g1[bf16] = dis[i] * (x @ W1)[i] ; packed 2 channels per uint, 8 uints/row
__global__ __launch_bounds__(256) void k_gemm1(const float* __restrict__ x,
                                               const float* __restrict__ W1,
                                               const float* __restrict__ dis,
                                               unsigned* __restrict__ g1) {
    __shared__ float xs[16][INC + 1];
    __shared__ float ws[INC][HID];
    __shared__ float accs[16][17];
    int t = threadIdx.x;
    int rowbase = blockIdx.x * 16;  // NN/16 = 6250 exact
#pragma unroll
    for (int i = 0; i < 8; ++i) {
        int idx = t + i * 256;
        xs[idx >> 7][idx & 127] = x[(long long)(rowbase)*INC + idx];
    }
#pragma unroll
    for (int i = 0; i < 8; ++i) {
        int idx = t + i * 256;
        ws[idx >> 4][idx & 15] = W1[idx];
    }
    __syncthreads();
    int r = t >> 4, c = t & 15;
    float acc = 0.f;
#pragma unroll
    for (int k = 0; k < INC; ++k) acc += xs[r][k] * ws[k][c];
    accs[r][c] = dis[rowbase + r] * acc;
    __syncthreads();
    if (t < 128) {
        int row = t >> 3, p = t & 7;
        g1[(rowbase + row) * 8 + p] = packbf(accs[row][2 * p], accs[row][2 * p + 1]);
    }
}

// layer-1 gather: g2[bf16] = relu(di*(sum g1[s] + g1[i]) + b1) * di
__global__ __launch_bounds__(256) void k_gather1(const unsigned* __restrict__ gin,
                                                 const float* __restrict__ dis,
                                                 const int* __restrict__ off,
                                                 const int* __restrict__ endv,
                                                 const int* __restrict__ bin,
                                                 const float* __restrict__ bias,
                                                 unsigned* __restrict__ outbf) {
    int t = threadIdx.x;
    int node = blockIdx.x * 64 + (t >> 2);
    if (node >= NN) return;
    int c4 = t & 3;
    const uint2* gv = (const uint2*)gin;
    uint2 u = gv[node * 4 + c4];  // self contribution
    float a0 = bflo(u.x), a1 = bfhi(u.x), a2 = bflo(u.y), a3 = bfhi(u.y);
    int j = off[node], end = endv[node];
    for (; j + 3 < end; j += 4) {
        int s0 = bin[j], s1 = bin[j + 1], s2 = bin[j + 2], s3 = bin[j + 3];
        uint2 u0 = gv[s0 * 4 + c4];
        uint2 u1 = gv[s1 * 4 + c4];
        uint2 u2 = gv[s2 * 4 + c4];
        uint2 u3 = gv[s3 * 4 + c4];
        a0 += (bflo(u0.x) + bflo(u1.x)) + (bflo(u2.x) + bflo(u3.x));
        a1 += (bfhi(u0.x) + bfhi(u1.x)) + (bfhi(u2.x) + bfhi(u3.x));
        a2 += (bflo(u0.y) + bflo(u1.y)) + (bflo(u2.y) + bflo(u3.y));
        a3 += (bfhi(u0.y) + bfhi(u1.y)) + (bfhi(u2.y) + bfhi(u3.y));
    }
    for (; j < end; ++j) {
        uint2 uu = gv[bin[j] * 4 + c4];
        a0 += bflo(uu.x); a1 += bfhi(uu.x); a2 += bflo(uu.y); a3 += bfhi(uu.y);
    }
    float di = dis[node];
    a0 = fmaxf(a0 * di + bias[c4 * 4 + 0], 0.f) * di;
    a1 = fmaxf(a1 * di + bias[c4 * 4 + 1], 0.f) * di;
    a2 = fmaxf(a2 * di + bias[c4 * 4 + 2], 0.f) * di;
    a3 = fmaxf(a3 * di + bias[c4 * 4 + 3], 0.f) * di;
    uint2 o; o.x = packbf(a0, a1); o.y = packbf(a2, a3);
    ((uint2*)outbf)[node * 4 + c4] = o;
}

// layer-2 gather fused with W2 GEMV + bias + log_softmax.
// Phase 1: 4 lanes/node accumulate 4 channels each -> LDS transpose.
// Phase 2: 4 lanes/node compute 10 logits each; 4-lane shfl reduce for lse.
__global__ __launch_bounds__(256) void k_gather2(const unsigned* __restrict__ gin,
                                                 const float* __restrict__ dis,
                                                 const int* __restrict__ off,
                                                 const int* __restrict__ endv,
                                                 const int* __restrict__ bin,
                                                 const float* __restrict__ W2,
                                                 const float* __restrict__ b2,
                                                 float* __restrict__ out) {
    __shared__ float accs[64][HID + 1];
    __shared__ float w2s[HID * OC];
    __shared__ float b2s[OC];
    int t = threadIdx.x;
    for (int i = t; i < HID * OC; i += 256) w2s[i] = W2[i];
    if (t < OC) b2s[t] = b2[t];
    int nl = t >> 2;
    int node = blockIdx.x * 64 + nl;
    int c4 = t & 3;
    if (node < NN) {
        const uint2* gv = (const uint2*)gin;
        uint2 u = gv[node * 4 + c4];  // self contribution
        float a0 = bflo(u.x), a1 = bfhi(u.x), a2 = bflo(u.y), a3 = bfhi(u.y);
        int j = off[node], end = endv[node];
        for (; j + 3 < end; j += 4) {
            int s0 = bin[j], s1 = bin[j + 1], s2 = bin[j + 2], s3 = bin[j + 3];
            uint2 u0 = gv[s0 * 4 + c4];
            uint2 u1 = gv[s1 * 4 + c4];
            uint2 u2 = gv[s2 * 4 + c4];
            uint2 u3 = gv[s3 * 4 + c4];
            a0 += (bflo(u0.x) + bflo(u1.x)) + (bflo(u2.x) + bflo(u3.x));
            a1 += (bfhi(u0.x) + bfhi(u1.x)) + (bfhi(u2.x) + bfhi(u3.x));
            a2 += (bflo(u0.y) + bflo(u1.y)) + (bflo(u2.y) + bflo(u3.y));
            a3 += (bfhi(u0.y) + bfhi(u1.y)) + (bfhi(u2.y) + bfhi(u3.y));
        }
        for (; j < end; ++j) {
            uint2 uu = gv[bin[j] * 4 + c4];
            a0 += bflo(uu.x); a1 += bfhi(uu.x); a2 += bflo(uu.y); a3 += bfhi(uu.y);
        }
        float di = dis[node];
        accs[nl][c4 * 4 + 0] = a0 * di;
        accs[nl][c4 * 4 + 1] = a1 * di;
        accs[nl][c4 * 4 + 2] = a2 * di;
        accs[nl][c4 * 4 + 3] = a3 * di;
    }
    __syncthreads();
    if (node >= NN) return;
    float a[HID];
#pragma unroll
    for (int k = 0; k < HID; ++k) a[k] = accs[nl][k];
    float z[10];
#pragma unroll
    for (int j = 0; j < 10; ++j) {
        int c = c4 * 10 + j;
        float zz = b2s[c];
#pragma unroll
        for (int k = 0; k < HID; ++k) zz += a[k] * w2s[k * OC + c];
        z[j] = zz;
    }
    float m = z[0];
#pragma unroll
    for (int j = 1; j < 10; ++j) m = fmaxf(m, z[j]);
    m = fmaxf(m, __shfl_xor(m, 1));
    m = fmaxf(m, __shfl_xor(m, 2));
    float s = 0.f;
#pragma unroll
    for (int j = 0; j < 10; ++j) s += expf(z[j] - m);
    s += __shfl_xor(s, 1);
    s += __shfl_xor(s, 2);
    float lse = m + logf(s);
    float* op = out + (size_t)node * OC + c4 * 10;
#pragma unroll
    for (int j = 0; j < 10; ++j) op[j] = z[j] - lse;
}

extern "C" void kernel_launch(void* const* d_in, const int* in_sizes, int n_in,
                              void* d_out, int out_size, void* d_ws, size_t ws_size,
                              hipStream_t stream) {
    const float* x  = (const float*)d_in[0];
    const int*   ei = (const int*)d_in[1];
    const float* W1 = (const float*)d_in[2];
    const float* b1 = (const float*)d_in[3];
    const float* W2 = (const float*)d_in[4];
    const float* b2 = (const float*)d_in[5];
    float* out = (float*)d_out;

    const int* src = ei;       // edge_index[0]
    const int* dst = ei + NE;  // edge_index[1]

    char* ws = (char*)d_ws;
    size_t o = 0;
    int*      cursor = (int*)(ws + o);      o += (size_t)NBK * CSTRIDE * 4;  // 25KB
    float*    dis    = (float*)(ws + o);    o += (size_t)NN * 4;             // 400KB
    int*      off    = (int*)(ws + o);      o += (size_t)NN * 4;             // 400KB
    int*      endv   = (int*)(ws + o);      o += (size_t)NN * 4;             // 400KB
    int*      bin    = (int*)(ws + o);      o += (size_t)NBK * CAP * 4;      // 14.0MB
    unsigned* gbf1   = (unsigned*)(ws + o); o += (size_t)NN * 8 * 4;         // 3.2MB
    unsigned* gbf2   = (unsigned*)(ws + o); o += (size_t)NN * 8 * 4;         // 3.2MB

    dim3 B(256);
    int gC = (NBK * CSTRIDE + 255) / 256;
    int gG = (NN + 63) / 64;

    k_zero_i<<<gC, B, 0, stream>>>(cursor, NBK * CSTRIDE);
    k_part<<<PBLK, 512, 0, stream>>>(src, dst, cursor, bin);
    k_bsort<<<NBK, 512, 0, stream>>>(bin, cursor, off, endv, dis);
    k_gemm1<<<NN / 16, B, 0, stream>>>(x, W1, dis, gbf1);
    k_gather1<<<gG, B, 0, stream>>>(gbf1, dis, off, endv, bin, b1, gbf2);
    k_gather2<<<gG, B, 0, stream>>>(gbf2, dis, off, endv, bin, W2, b2, out);
}